// Round 3
// baseline (411.889 us; speedup 1.0000x reference)
//
#include <hip/hip_runtime.h>
#include <hip/hip_fp16.h>
#include <math.h>

// GCN: h1 = relu(Agg(x@W1)+b1); h2 = relu(Agg(h1@W2)+b2); pooled = segment_mean(h2);
// out = log_softmax(relu(pooled@fc1+b)@fc2+b)
// buf8[s] = fp8(dis[s] * (x@W)[s]); Agg(v) = relu(dis[v]*(row_v + sum row_s) + b).
// CSR: fixed per-bucket stride (PCAP); per-node lists padded to multiple of 16 with
// dummy src=N -> zero row; agg is one uniform 8-deep loop. Node extents via explicit
// rowbeg/rowend.
// R2 post-mortem: agg1+gemm2 fusion REGRESSED (63.4 vs 40.4+12.3 us) — barrier +
// 4-nodes-serial-per-wave killed gather MLP (hbm_gbps 2924->1582 at same fetch).
// Reverted. agg itself is L3-rooflined (92.5MB L2-miss == 8 XCD x 12.8MB floor).
// R3: binA/binB (bucket-major LDS-atomic binning + 25.6MB binned round-trip, 196-block
// serial binB) replaced by direct global-atomic CSR build: deg -> scan(+dummy pad) ->
// scatter. Same strided-padded layout; agg/gemm untouched. CSR per-node order changes
// (atomic order) — sum is order-insensitive within tolerance.

#define D_FEAT 128
#define BSHIFT 9
#define BNODES 512
#define PCAP 16384

using half8   = __attribute__((ext_vector_type(8))) _Float16;
using half4   = __attribute__((ext_vector_type(4))) _Float16;
using floatx4 = __attribute__((ext_vector_type(4))) float;
using floatx2 = __attribute__((ext_vector_type(2))) float;

// ---- degree count: 1.6M global atomics, uniform over 400KB (no hotspot) ----
__global__ void __launch_bounds__(256) deg_kernel(const int* __restrict__ edges,
                                                  int* __restrict__ deg, int E) {
    int i = (blockIdx.x * 256 + threadIdx.x) * 4;
    if (i + 3 < E) {
        int4 d4 = *(const int4*)&edges[E + i];
        atomicAdd(&deg[d4.x], 1);
        atomicAdd(&deg[d4.y], 1);
        atomicAdd(&deg[d4.z], 1);
        atomicAdd(&deg[d4.w], 1);
    } else {
        for (; i < E; ++i) atomicAdd(&deg[edges[E + i]], 1);
    }
}

// ---- per-bucket scan: pad-to-16 sizes -> rowbeg/rowend/cur/dis + dummy slots ----
// One block (256 thr) per 512-node bucket; dummy positions known from deg, written here.
__global__ void __launch_bounds__(256) scan_kernel(const int* __restrict__ deg,
                                                   float* __restrict__ dis,
                                                   int* __restrict__ rowbeg,
                                                   int* __restrict__ rowend,
                                                   int* __restrict__ cur,
                                                   int* __restrict__ csr, int N) {
    __shared__ int sdata[256];
    int t = threadIdx.x;
    int b = blockIdx.x;
    int node0 = b << BSHIFT;
    int n0 = node0 + 2 * t, n1 = node0 + 2 * t + 1;
    int a0 = (n0 < N) ? deg[n0] : 0;
    int a1 = (n1 < N) ? deg[n1] : 0;
    int p0sz = (a0 + 15) & ~15, p1sz = (a1 + 15) & ~15;   // pad to multiple of 16
    int pair = p0sz + p1sz;
    sdata[t] = pair;
    __syncthreads();
    for (int d = 1; d < 256; d <<= 1) {
        int u = (t >= d) ? sdata[t - d] : 0;
        __syncthreads();
        sdata[t] += u;
        __syncthreads();
    }
    int excl = sdata[t] - pair;
    int q0 = b * PCAP + excl, q1 = q0 + p0sz;
    if (n0 < N) {
        rowbeg[n0] = q0; rowend[n0] = q1; cur[n0] = q0;
        dis[n0] = rsqrtf((float)a0 + 1.0f);
        for (int p = q0 + a0; p < q1; ++p) csr[p] = N;    // dummy -> zero row
    }
    if (n1 < N) {
        rowbeg[n1] = q1; rowend[n1] = q1 + p1sz; cur[n1] = q1;
        dis[n1] = rsqrtf((float)a1 + 1.0f);
        for (int p = q1 + a1; p < q1 + p1sz; ++p) csr[p] = N;
    }
}

// ---- scatter: csr[fetch_add(cur[dst])] = src ----
__global__ void __launch_bounds__(256) scat_kernel(const int* __restrict__ edges,
                                                   int* __restrict__ cur,
                                                   int* __restrict__ csr, int E) {
    int i = (blockIdx.x * 256 + threadIdx.x) * 4;
    if (i + 3 < E) {
        int4 s4 = *(const int4*)&edges[i];
        int4 d4 = *(const int4*)&edges[E + i];
        csr[atomicAdd(&cur[d4.x], 1)] = s4.x;
        csr[atomicAdd(&cur[d4.y], 1)] = s4.y;
        csr[atomicAdd(&cur[d4.z], 1)] = s4.z;
        csr[atomicAdd(&cur[d4.w], 1)] = s4.w;
    } else {
        for (; i < E; ++i) csr[atomicAdd(&cur[edges[E + i]], 1)] = edges[i];
    }
}

// W transpose + fp32->fp16; also zeroes buf8 row N (dummy target)
__global__ void wprep_kernel(const float* __restrict__ W1, const float* __restrict__ W2,
                             _Float16* __restrict__ Wt1, _Float16* __restrict__ Wt2,
                             unsigned int* __restrict__ zrow) {
    int i = blockIdx.x * blockDim.x + threadIdx.x;
    int n = i >> 7, k = i & 127;
    Wt1[i] = (_Float16)W1[k * 128 + n];
    Wt2[i] = (_Float16)W2[k * 128 + n];
    if (i < 32) zrow[i] = 0u;
}

// Y8[row,:] = fp8_e4m3( dis[row] * (X[row,:] @ W) ) via fp16 MFMA.
template <bool HALF_IN>
__global__ void __launch_bounds__(256) gemm_mfma_kernel(const void* __restrict__ Xv,
                                                        const _Float16* __restrict__ WtG,
                                                        const float* __restrict__ dis,
                                                        unsigned char* __restrict__ Y8, int N) {
    __shared__ _Float16 wt[128][136];
    int t = threadIdx.x;
    int row0 = blockIdx.x * 64;

#pragma unroll
    for (int i = 0; i < 8; ++i) {
        int c = t + i * 256;
        int r = c >> 4, c8 = (c & 15) * 8;
        *(half8*)&wt[r][c8] = *(const half8*)&WtG[r * 128 + c8];
    }

    int wave = t >> 6, lane = t & 63;
    int m = lane & 15, quad = lane >> 4;
    int grow = row0 + wave * 16 + m;

    half8 a[4];
    if (grow < N) {
        if (HALF_IN) {
            const _Float16* Xp = (const _Float16*)Xv;
#pragma unroll
            for (int k = 0; k < 4; ++k)
                a[k] = *(const half8*)&Xp[(size_t)grow * 128 + k * 32 + quad * 8];
        } else {
            const float* Xp = (const float*)Xv;
#pragma unroll
            for (int k = 0; k < 4; ++k) {
                float4 v0 = *(const float4*)&Xp[(size_t)grow * 128 + k * 32 + quad * 8];
                float4 v1 = *(const float4*)&Xp[(size_t)grow * 128 + k * 32 + quad * 8 + 4];
                a[k] = (half8){(_Float16)v0.x, (_Float16)v0.y, (_Float16)v0.z, (_Float16)v0.w,
                               (_Float16)v1.x, (_Float16)v1.y, (_Float16)v1.z, (_Float16)v1.w};
            }
        }
    } else {
#pragma unroll
        for (int k = 0; k < 4; ++k) a[k] = (half8){};
    }
    __syncthreads();

    floatx4 acc[8];
#pragma unroll
    for (int nt = 0; nt < 8; ++nt) acc[nt] = (floatx4){0.f, 0.f, 0.f, 0.f};
#pragma unroll
    for (int nt = 0; nt < 8; ++nt) {
#pragma unroll
        for (int k = 0; k < 4; ++k) {
            half8 bfr = *(const half8*)&wt[nt * 16 + m][k * 32 + quad * 8];
            acc[nt] = __builtin_amdgcn_mfma_f32_16x16x32_f16(a[k], bfr, acc[nt], 0, 0, 0);
        }
    }
    int orow = row0 + wave * 16 + quad * 4;
#pragma unroll
    for (int r = 0; r < 4; ++r) {
        int row = orow + r;
        if (row < N) {
            float dr = dis[row];
#pragma unroll
            for (int nt = 0; nt < 8; ++nt) {
                float v = acc[nt][r] * dr;
                unsigned char q =
                    (unsigned char)(__builtin_amdgcn_cvt_pk_fp8_f32(v, v, 0, false) & 0xff);
                Y8[(size_t)row * 128 + nt * 16 + m] = q;
            }
        }
    }
}

// One wave per dst node over pre-scaled fp8 rows; half-wave per edge, plain adds.
// CSR padded to multiple of 16 per node (dummies -> zero row): single uniform loop.
__global__ void __launch_bounds__(256) agg_kernel(const unsigned char* __restrict__ H8,
                                                  const int* __restrict__ rowbeg,
                                                  const int* __restrict__ rowend,
                                                  const int* __restrict__ csr,
                                                  const float* __restrict__ dis,
                                                  const float* __restrict__ bias,
                                                  _Float16* __restrict__ out, int N) {
    int v = (blockIdx.x * blockDim.x + threadIdx.x) >> 6;
    int lane = threadIdx.x & 63;
    if (v >= N) return;
    int half = lane >> 5, sl = lane & 31;
    int r0 = rowbeg[v], r1 = rowend[v];
    float dv = dis[v];
    unsigned fo = (unsigned)(sl << 2);

    floatx2 a01, a23;
    {   // self row (pre-scaled): each half adds 0.5x, sums to 1x after combine
        unsigned int u = *(const unsigned int*)(H8 + (((unsigned)v << 7) | fo));
        floatx2 lo = __builtin_amdgcn_cvt_pk_f32_fp8(u, false);
        floatx2 hi = __builtin_amdgcn_cvt_pk_f32_fp8(u, true);
        floatx2 hf = {0.5f, 0.5f};
        a01 = hf * lo;
        a23 = hf * hi;
    }
#define ACC(uu)                                                         \
        {                                                               \
            a01 += __builtin_amdgcn_cvt_pk_f32_fp8(uu, false);          \
            a23 += __builtin_amdgcn_cvt_pk_f32_fp8(uu, true);           \
        }
    for (int e = r0 + half; e + 14 < r1; e += 16) {   // uniform: 8 edges per half
        int s0 = csr[e],      s1 = csr[e + 2],  s2 = csr[e + 4],  s3 = csr[e + 6];
        int s4 = csr[e + 8],  s5 = csr[e + 10], s6 = csr[e + 12], s7 = csr[e + 14];
        unsigned int u0 = *(const unsigned int*)(H8 + (((unsigned)s0 << 7) | fo));
        unsigned int u1 = *(const unsigned int*)(H8 + (((unsigned)s1 << 7) | fo));
        unsigned int u2 = *(const unsigned int*)(H8 + (((unsigned)s2 << 7) | fo));
        unsigned int u3 = *(const unsigned int*)(H8 + (((unsigned)s3 << 7) | fo));
        unsigned int u4 = *(const unsigned int*)(H8 + (((unsigned)s4 << 7) | fo));
        unsigned int u5 = *(const unsigned int*)(H8 + (((unsigned)s5 << 7) | fo));
        unsigned int u6 = *(const unsigned int*)(H8 + (((unsigned)s6 << 7) | fo));
        unsigned int u7 = *(const unsigned int*)(H8 + (((unsigned)s7 << 7) | fo));
        ACC(u0) ACC(u1) ACC(u2) ACC(u3) ACC(u4) ACC(u5) ACC(u6) ACC(u7)
    }
#undef ACC
    a01[0] += __shfl_xor(a01[0], 32, 64);
    a01[1] += __shfl_xor(a01[1], 32, 64);
    a23[0] += __shfl_xor(a23[0], 32, 64);
    a23[1] += __shfl_xor(a23[1], 32, 64);
    if (half == 0) {
        float4 b = *(const float4*)&bias[sl * 4];
        half4 o = {(_Float16)fmaxf(dv * a01[0] + b.x, 0.f),
                   (_Float16)fmaxf(dv * a01[1] + b.y, 0.f),
                   (_Float16)fmaxf(dv * a23[0] + b.z, 0.f),
                   (_Float16)fmaxf(dv * a23[1] + b.w, 0.f)};
        *(half4*)&out[(size_t)v * 128 + sl * 4] = o;
    }
}

__device__ __forceinline__ int lower_bound_i(const int* a, int n, int key) {
    int lo = 0, hi = n;
    while (lo < hi) {
        int mid = (lo + hi) >> 1;
        if (a[mid] < key) lo = mid + 1;
        else hi = mid;
    }
    return lo;
}

// Fused pool + head: one block (512 thr) per graph.
__global__ void __launch_bounds__(512) poolhead_kernel(const _Float16* __restrict__ H,
                                                       const int* __restrict__ batch,
                                                       const float* __restrict__ fc1w,
                                                       const float* __restrict__ fc1b,
                                                       const float* __restrict__ fc2w,
                                                       const float* __restrict__ fc2b,
                                                       float* __restrict__ out, int N) {
    __shared__ int range[2];
    __shared__ float part[4][128];
    __shared__ float p[128];
    __shared__ float r0s[128], r1s[128];
    int g = blockIdx.x;
    int t = threadIdx.x;
    int j = t & 127, rg = t >> 7;
    if (t < 2) range[t] = lower_bound_i(batch, N, g + t);
    __syncthreads();
    int lo = range[0], hi = range[1];
    float s = 0.f;
    for (int v = lo + rg; v < hi; v += 4) s += (float)H[(size_t)v * 128 + j];
    part[rg][j] = s;
    __syncthreads();
    if (rg == 0) {
        float tot = part[0][j] + part[1][j] + part[2][j] + part[3][j];
        p[j] = tot / fmaxf((float)(hi - lo), 1.0f);
    }
    __syncthreads();
    if (t < 128) {
        float acc = fc1b[t];
#pragma unroll 8
        for (int k = 0; k < 128; ++k) acc = fmaf(p[k], fc1w[k * 128 + t], acc);
        float gv = fmaxf(acc, 0.f);
        r0s[t] = gv * fc2w[t * 2 + 0];
        r1s[t] = gv * fc2w[t * 2 + 1];
    }
    __syncthreads();
    for (int st = 64; st > 0; st >>= 1) {
        if (t < st) {
            r0s[t] += r0s[t + st];
            r1s[t] += r1s[t + st];
        }
        __syncthreads();
    }
    if (t == 0) {
        float l0 = r0s[0] + fc2b[0];
        float l1 = r1s[0] + fc2b[1];
        float m = fmaxf(l0, l1);
        float lse = m + logf(expf(l0 - m) + expf(l1 - m));
        out[g * 2 + 0] = l0 - lse;
        out[g * 2 + 1] = l1 - lse;
    }
}

extern "C" void kernel_launch(void* const* d_in, const int* in_sizes, int n_in,
                              void* d_out, int out_size, void* d_ws, size_t ws_size,
                              hipStream_t stream) {
    const float* x    = (const float*)d_in[0];
    const int* edges  = (const int*)d_in[1];
    const int* batch  = (const int*)d_in[2];
    const float* W1   = (const float*)d_in[3];
    const float* b1   = (const float*)d_in[4];
    const float* W2   = (const float*)d_in[5];
    const float* b2   = (const float*)d_in[6];
    const float* fc1w = (const float*)d_in[7];
    const float* fc1b = (const float*)d_in[8];
    const float* fc2w = (const float*)d_in[9];
    const float* fc2b = (const float*)d_in[10];
    float* out = (float*)d_out;

    int N = in_sizes[2];        // 100000
    int E = in_sizes[1] / 2;    // 1600000
    int G = out_size / 2;       // 1024
    int nb = (N + BNODES - 1) / BNODES;   // 196

    char* ws = (char*)d_ws;
    size_t off = 0;
    auto alloc = [&](size_t bytes) -> char* {
        char* ptr = ws + off;
        off += (bytes + 255) & ~(size_t)255;
        return ptr;
    };
    int* deg           = (int*)alloc((size_t)N * 4);
    int* cur           = (int*)alloc((size_t)N * 4);
    int* rowbeg        = (int*)alloc((size_t)N * 4);
    int* rowend        = (int*)alloc((size_t)N * 4);
    float* dis         = (float*)alloc((size_t)N * 4);
    int* csr           = (int*)alloc((size_t)nb * PCAP * 4);
    _Float16* Wt1      = (_Float16*)alloc(128 * 128 * 2);
    _Float16* Wt2      = (_Float16*)alloc(128 * 128 * 2);
    unsigned char* buf8 = (unsigned char*)alloc((size_t)(N + 1) * D_FEAT);  // +1 zero row
    _Float16* bufH     = (_Float16*)alloc((size_t)N * D_FEAT * 2);

    hipMemsetAsync(deg, 0, (size_t)N * 4, stream);

    int gE4 = (E / 4 + 255) / 256;   // 1563
    deg_kernel<<<gE4, 256, 0, stream>>>(edges, deg, E);
    scan_kernel<<<nb, 256, 0, stream>>>(deg, dis, rowbeg, rowend, cur, csr, N);
    scat_kernel<<<gE4, 256, 0, stream>>>(edges, cur, csr, E);
    wprep_kernel<<<64, 256, 0, stream>>>(W1, W2, Wt1, Wt2,
                                         (unsigned int*)(buf8 + (size_t)N * D_FEAT));

    int gAgg = (N * 64 + 255) / 256;
    int gGemm = (N + 63) / 64;
    gemm_mfma_kernel<false><<<gGemm, 256, 0, stream>>>((const void*)x, Wt1, dis, buf8, N);
    agg_kernel<<<gAgg, 256, 0, stream>>>(buf8, rowbeg, rowend, csr, dis, b1, bufH, N);
    gemm_mfma_kernel<true><<<gGemm, 256, 0, stream>>>((const void*)bufH, Wt2, dis, buf8, N);
    agg_kernel<<<gAgg, 256, 0, stream>>>(buf8, rowbeg, rowend, csr, dis, b2, bufH, N);
    poolhead_kernel<<<G, 512, 0, stream>>>(bufH, batch, fc1w, fc1b, fc2w, fc2b, out, N);
}

// Round 5
// 267.990 us; speedup vs baseline: 1.5370x; 1.5370x over previous
//
#include <hip/hip_runtime.h>
#include <hip/hip_fp16.h>
#include <math.h>

// GCN: h1 = relu(Agg(x@W1)+b1); h2 = relu(Agg(h1@W2)+b2); pooled = segment_mean(h2);
// out = log_softmax(relu(pooled@fc1+b)@fc2+b)
// buf8[s] = fp8(dis[s] * (x@W)[s]); Agg(v) = relu(dis[v]*(row_v + sum row_s) + b).
// CSR: fixed per-bucket stride (PCAP); per-node lists padded to multiple of 16 with
// dummy src=N -> zero row; agg is one uniform loop. Node extents via packed rowext.
// R2: agg1+gemm2 fusion REGRESSED (63.4 us) — barrier serialized gather MLP. Reverted.
// R3: global-atomic CSR build REGRESSED (scat 127 us: value-returning device atomics
// ~12M/s). Reverted to LDS binning (binA+binB ~25 us total).
// R4: agg is LATENCY-bound (92.5MB@2.3TB/s << L3 ~17TB/s; VALUBusy 40%): (a) packed
// rowext int4 {beg,end,dis-bits} single 16B load; (b) csr read as 4x int4 (row start
// 64B-aligned by construction) + next-16 prefetch pipeline; (c) 128-thr blocks to cut
// straggler tail.

#define D_FEAT 128
#define BSHIFT 9
#define BNODES 512
#define CHUNK 4096
#define CAPB 16384
#define PCAP 16384
#define CAP 10240

using half8   = __attribute__((ext_vector_type(8))) _Float16;
using half4   = __attribute__((ext_vector_type(4))) _Float16;
using floatx4 = __attribute__((ext_vector_type(4))) float;
using floatx2 = __attribute__((ext_vector_type(2))) float;

// ---- single-pass binning: binned[b*CAPB + pos] = (dstlow<<17)|src ----
__global__ void __launch_bounds__(256) binA_kernel(const int* __restrict__ edges,
                                                   int* __restrict__ gcur,
                                                   int* __restrict__ binned, int E, int nb) {
    __shared__ int h[256];
    __shared__ int cur[256];
    __shared__ int base[256];
    int t = threadIdx.x;
    int c0 = blockIdx.x * CHUNK;
    int sv[CHUNK / 256], bv[CHUNK / 256];
    int i0 = c0 + t * (CHUNK / 256);
    if (i0 + (CHUNK / 256) <= E) {
#pragma unroll
        for (int k = 0; k < CHUNK / 256; k += 4) {
            int4 s4 = *(const int4*)&edges[i0 + k];
            int4 d4 = *(const int4*)&edges[E + i0 + k];
            bv[k + 0] = d4.x >> BSHIFT; sv[k + 0] = ((d4.x & (BNODES - 1)) << 17) | s4.x;
            bv[k + 1] = d4.y >> BSHIFT; sv[k + 1] = ((d4.y & (BNODES - 1)) << 17) | s4.y;
            bv[k + 2] = d4.z >> BSHIFT; sv[k + 2] = ((d4.z & (BNODES - 1)) << 17) | s4.z;
            bv[k + 3] = d4.w >> BSHIFT; sv[k + 3] = ((d4.w & (BNODES - 1)) << 17) | s4.w;
        }
    } else {
#pragma unroll
        for (int k = 0; k < CHUNK / 256; ++k) {
            int i = i0 + k;
            if (i < E) {
                int s = edges[i], d = edges[E + i];
                bv[k] = d >> BSHIFT;
                sv[k] = ((d & (BNODES - 1)) << 17) | s;
            } else bv[k] = -1;
        }
    }
    h[t] = 0;
    __syncthreads();
#pragma unroll
    for (int k = 0; k < CHUNK / 256; ++k)
        if (bv[k] >= 0) atomicAdd(&h[bv[k]], 1);
    __syncthreads();
    if (t < nb && h[t] > 0) base[t] = atomicAdd(&gcur[t], h[t]);
    cur[t] = 0;
    __syncthreads();
#pragma unroll
    for (int k = 0; k < CHUNK / 256; ++k)
        if (bv[k] >= 0) {
            int b = bv[k];
            int r = atomicAdd(&cur[b], 1);
            int pos = base[b] + r;
            if (pos < CAPB) binned[b * CAPB + pos] = sv[k];
        }
}

// ---- binB (fused): per bucket: hist -> dis/rowext, scatter reals, pad dummies ----
__global__ void __launch_bounds__(256) binB_kernel(const int* __restrict__ binned,
                                                   const int* __restrict__ gcur,
                                                   float* __restrict__ dis,
                                                   int4* __restrict__ rowext,
                                                   int* __restrict__ csr,
                                                   int N, int nb) {
    __shared__ int hist[BNODES];
    __shared__ int cur[BNODES];
    __shared__ int pend[BNODES];
    __shared__ int sdata[256];
    __shared__ int vals[CAP];
    int t = threadIdx.x;
    int b = blockIdx.x;
    int node0 = b << BSHIFT;
    int cnt = gcur[b];
    const int* bin = binned + (size_t)b * CAPB;
    hist[t] = 0; hist[t + 256] = 0;
    __syncthreads();
    for (int i = t; i < cnt; i += 256) {
        int v = bin[i];
        if (i < CAP) vals[i] = v;
        atomicAdd(&hist[v >> 17], 1);
    }
    __syncthreads();
    int a0 = hist[2 * t], a1 = hist[2 * t + 1];
    int p0sz = (a0 + 15) & ~15, p1sz = (a1 + 15) & ~15;   // pad to multiple of 16
    int pair = p0sz + p1sz;
    sdata[t] = pair;
    __syncthreads();
    for (int d = 1; d < 256; d <<= 1) {
        int u = (t >= d) ? sdata[t - d] : 0;
        __syncthreads();
        sdata[t] += u;
        __syncthreads();
    }
    int excl = sdata[t] - pair;
    int q0 = b * PCAP + excl, q1 = q0 + p0sz;
    cur[2 * t] = q0;
    cur[2 * t + 1] = q1;
    pend[2 * t] = q1;
    pend[2 * t + 1] = q1 + p1sz;
    int n0 = node0 + 2 * t, n1 = node0 + 2 * t + 1;
    if (n0 < N) {
        float d0 = rsqrtf((float)a0 + 1.0f);
        dis[n0] = d0;
        rowext[n0] = (int4){q0, q1, __float_as_int(d0), 0};
    }
    if (n1 < N) {
        float d1 = rsqrtf((float)a1 + 1.0f);
        dis[n1] = d1;
        rowext[n1] = (int4){q1, q1 + p1sz, __float_as_int(d1), 0};
    }
    __syncthreads();
    for (int i = t; i < cnt; i += 256) {
        int v = (i < CAP) ? vals[i] : bin[i];
        int p = atomicAdd(&cur[v >> 17], 1);
        csr[p] = v & 0x1FFFF;
    }
    __syncthreads();
    for (int i = t; i < BNODES; i += 256) {
        int e = pend[i];
        for (int p = cur[i]; p < e; ++p) csr[p] = N;   // dummy -> zero row
    }
}

// W transpose + fp32->fp16; also zeroes buf8 row N (dummy target)
__global__ void wprep_kernel(const float* __restrict__ W1, const float* __restrict__ W2,
                             _Float16* __restrict__ Wt1, _Float16* __restrict__ Wt2,
                             unsigned int* __restrict__ zrow) {
    int i = blockIdx.x * blockDim.x + threadIdx.x;
    int n = i >> 7, k = i & 127;
    Wt1[i] = (_Float16)W1[k * 128 + n];
    Wt2[i] = (_Float16)W2[k * 128 + n];
    if (i < 32) zrow[i] = 0u;
}

// Y8[row,:] = fp8_e4m3( dis[row] * (X[row,:] @ W) ) via fp16 MFMA.
template <bool HALF_IN>
__global__ void __launch_bounds__(256) gemm_mfma_kernel(const void* __restrict__ Xv,
                                                        const _Float16* __restrict__ WtG,
                                                        const float* __restrict__ dis,
                                                        unsigned char* __restrict__ Y8, int N) {
    __shared__ _Float16 wt[128][136];
    int t = threadIdx.x;
    int row0 = blockIdx.x * 64;

#pragma unroll
    for (int i = 0; i < 8; ++i) {
        int c = t + i * 256;
        int r = c >> 4, c8 = (c & 15) * 8;
        *(half8*)&wt[r][c8] = *(const half8*)&WtG[r * 128 + c8];
    }

    int wave = t >> 6, lane = t & 63;
    int m = lane & 15, quad = lane >> 4;
    int grow = row0 + wave * 16 + m;

    half8 a[4];
    if (grow < N) {
        if (HALF_IN) {
            const _Float16* Xp = (const _Float16*)Xv;
#pragma unroll
            for (int k = 0; k < 4; ++k)
                a[k] = *(const half8*)&Xp[(size_t)grow * 128 + k * 32 + quad * 8];
        } else {
            const float* Xp = (const float*)Xv;
#pragma unroll
            for (int k = 0; k < 4; ++k) {
                float4 v0 = *(const float4*)&Xp[(size_t)grow * 128 + k * 32 + quad * 8];
                float4 v1 = *(const float4*)&Xp[(size_t)grow * 128 + k * 32 + quad * 8 + 4];
                a[k] = (half8){(_Float16)v0.x, (_Float16)v0.y, (_Float16)v0.z, (_Float16)v0.w,
                               (_Float16)v1.x, (_Float16)v1.y, (_Float16)v1.z, (_Float16)v1.w};
            }
        }
    } else {
#pragma unroll
        for (int k = 0; k < 4; ++k) a[k] = (half8){};
    }
    __syncthreads();

    floatx4 acc[8];
#pragma unroll
    for (int nt = 0; nt < 8; ++nt) acc[nt] = (floatx4){0.f, 0.f, 0.f, 0.f};
#pragma unroll
    for (int nt = 0; nt < 8; ++nt) {
#pragma unroll
        for (int k = 0; k < 4; ++k) {
            half8 bfr = *(const half8*)&wt[nt * 16 + m][k * 32 + quad * 8];
            acc[nt] = __builtin_amdgcn_mfma_f32_16x16x32_f16(a[k], bfr, acc[nt], 0, 0, 0);
        }
    }
    int orow = row0 + wave * 16 + quad * 4;
#pragma unroll
    for (int r = 0; r < 4; ++r) {
        int row = orow + r;
        if (row < N) {
            float dr = dis[row];
#pragma unroll
            for (int nt = 0; nt < 8; ++nt) {
                float v = acc[nt][r] * dr;
                unsigned char q =
                    (unsigned char)(__builtin_amdgcn_cvt_pk_fp8_f32(v, v, 0, false) & 0xff);
                Y8[(size_t)row * 128 + nt * 16 + m] = q;
            }
        }
    }
}

// One wave per dst node over pre-scaled fp8 rows; half-wave per edge, plain adds.
// R4: packed rowext (1x16B load), csr via wave-uniform int4 (64B-aligned rows) with
// next-16 prefetch, 128-thread blocks.
__global__ void __launch_bounds__(128) agg_kernel(const unsigned char* __restrict__ H8,
                                                  const int4* __restrict__ rowext,
                                                  const int* __restrict__ csr,
                                                  const float* __restrict__ bias,
                                                  _Float16* __restrict__ out, int N) {
    int v = (blockIdx.x * 128 + threadIdx.x) >> 6;
    int lane = threadIdx.x & 63;
    if (v >= N) return;
    int half = lane >> 5, sl = lane & 31;
    int4 re = rowext[v];
    int r0 = re.x, len = re.y - re.x;
    float dv = __int_as_float(re.z);
    unsigned fo = (unsigned)(sl << 2);

    floatx2 a01, a23;
    {   // self row (pre-scaled): each half adds 0.5x, sums to 1x after combine
        unsigned int u = *(const unsigned int*)(H8 + (((unsigned)v << 7) | fo));
        floatx2 lo = __builtin_amdgcn_cvt_pk_f32_fp8(u, false);
        floatx2 hi = __builtin_amdgcn_cvt_pk_f32_fp8(u, true);
        floatx2 hf = {0.5f, 0.5f};
        a01 = hf * lo;
        a23 = hf * hi;
    }
    const int4* cp = (const int4*)(csr + r0);   // 64B-aligned: r0 = bucket*PCAP + 16k
    int4 cb0, cb1, cb2, cb3;
    if (len > 0) { cb0 = cp[0]; cb1 = cp[1]; cb2 = cp[2]; cb3 = cp[3]; }
#define ACC(uu)                                                         \
        {                                                               \
            a01 += __builtin_amdgcn_cvt_pk_f32_fp8(uu, false);          \
            a23 += __builtin_amdgcn_cvt_pk_f32_fp8(uu, true);           \
        }
    for (int base = 0; base < len; base += 16) {
        int4 c0 = cb0, c1 = cb1, c2 = cb2, c3 = cb3;
        if (base + 16 < len) {
            const int4* np = cp + ((base >> 4) + 1) * 4;
            cb0 = np[0]; cb1 = np[1]; cb2 = np[2]; cb3 = np[3];
        }
        int s0 = half ? c0.y : c0.x,  s1 = half ? c0.w : c0.z;
        int s2 = half ? c1.y : c1.x,  s3 = half ? c1.w : c1.z;
        int s4 = half ? c2.y : c2.x,  s5 = half ? c2.w : c2.z;
        int s6 = half ? c3.y : c3.x,  s7 = half ? c3.w : c3.z;
        unsigned int u0 = *(const unsigned int*)(H8 + (((unsigned)s0 << 7) | fo));
        unsigned int u1 = *(const unsigned int*)(H8 + (((unsigned)s1 << 7) | fo));
        unsigned int u2 = *(const unsigned int*)(H8 + (((unsigned)s2 << 7) | fo));
        unsigned int u3 = *(const unsigned int*)(H8 + (((unsigned)s3 << 7) | fo));
        unsigned int u4 = *(const unsigned int*)(H8 + (((unsigned)s4 << 7) | fo));
        unsigned int u5 = *(const unsigned int*)(H8 + (((unsigned)s5 << 7) | fo));
        unsigned int u6 = *(const unsigned int*)(H8 + (((unsigned)s6 << 7) | fo));
        unsigned int u7 = *(const unsigned int*)(H8 + (((unsigned)s7 << 7) | fo));
        ACC(u0) ACC(u1) ACC(u2) ACC(u3) ACC(u4) ACC(u5) ACC(u6) ACC(u7)
    }
#undef ACC
    a01[0] += __shfl_xor(a01[0], 32, 64);
    a01[1] += __shfl_xor(a01[1], 32, 64);
    a23[0] += __shfl_xor(a23[0], 32, 64);
    a23[1] += __shfl_xor(a23[1], 32, 64);
    if (half == 0) {
        float4 b = *(const float4*)&bias[sl * 4];
        half4 o = {(_Float16)fmaxf(dv * a01[0] + b.x, 0.f),
                   (_Float16)fmaxf(dv * a01[1] + b.y, 0.f),
                   (_Float16)fmaxf(dv * a23[0] + b.z, 0.f),
                   (_Float16)fmaxf(dv * a23[1] + b.w, 0.f)};
        *(half4*)&out[(size_t)v * 128 + sl * 4] = o;
    }
}

__device__ __forceinline__ int lower_bound_i(const int* a, int n, int key) {
    int lo = 0, hi = n;
    while (lo < hi) {
        int mid = (lo + hi) >> 1;
        if (a[mid] < key) lo = mid + 1;
        else hi = mid;
    }
    return lo;
}

// Fused pool + head: one block (512 thr) per graph.
__global__ void __launch_bounds__(512) poolhead_kernel(const _Float16* __restrict__ H,
                                                       const int* __restrict__ batch,
                                                       const float* __restrict__ fc1w,
                                                       const float* __restrict__ fc1b,
                                                       const float* __restrict__ fc2w,
                                                       const float* __restrict__ fc2b,
                                                       float* __restrict__ out, int N) {
    __shared__ int range[2];
    __shared__ float part[4][128];
    __shared__ float p[128];
    __shared__ float r0s[128], r1s[128];
    int g = blockIdx.x;
    int t = threadIdx.x;
    int j = t & 127, rg = t >> 7;
    if (t < 2) range[t] = lower_bound_i(batch, N, g + t);
    __syncthreads();
    int lo = range[0], hi = range[1];
    float s = 0.f;
    for (int v = lo + rg; v < hi; v += 4) s += (float)H[(size_t)v * 128 + j];
    part[rg][j] = s;
    __syncthreads();
    if (rg == 0) {
        float tot = part[0][j] + part[1][j] + part[2][j] + part[3][j];
        p[j] = tot / fmaxf((float)(hi - lo), 1.0f);
    }
    __syncthreads();
    if (t < 128) {
        float acc = fc1b[t];
#pragma unroll 8
        for (int k = 0; k < 128; ++k) acc = fmaf(p[k], fc1w[k * 128 + t], acc);
        float gv = fmaxf(acc, 0.f);
        r0s[t] = gv * fc2w[t * 2 + 0];
        r1s[t] = gv * fc2w[t * 2 + 1];
    }
    __syncthreads();
    for (int st = 64; st > 0; st >>= 1) {
        if (t < st) {
            r0s[t] += r0s[t + st];
            r1s[t] += r1s[t + st];
        }
        __syncthreads();
    }
    if (t == 0) {
        float l0 = r0s[0] + fc2b[0];
        float l1 = r1s[0] + fc2b[1];
        float m = fmaxf(l0, l1);
        float lse = m + logf(expf(l0 - m) + expf(l1 - m));
        out[g * 2 + 0] = l0 - lse;
        out[g * 2 + 1] = l1 - lse;
    }
}

extern "C" void kernel_launch(void* const* d_in, const int* in_sizes, int n_in,
                              void* d_out, int out_size, void* d_ws, size_t ws_size,
                              hipStream_t stream) {
    const float* x    = (const float*)d_in[0];
    const int* edges  = (const int*)d_in[1];
    const int* batch  = (const int*)d_in[2];
    const float* W1   = (const float*)d_in[3];
    const float* b1   = (const float*)d_in[4];
    const float* W2   = (const float*)d_in[5];
    const float* b2   = (const float*)d_in[6];
    const float* fc1w = (const float*)d_in[7];
    const float* fc1b = (const float*)d_in[8];
    const float* fc2w = (const float*)d_in[9];
    const float* fc2b = (const float*)d_in[10];
    float* out = (float*)d_out;

    int N = in_sizes[2];        // 100000
    int E = in_sizes[1] / 2;    // 1600000
    int G = out_size / 2;       // 1024
    int nb = (N + BNODES - 1) / BNODES;   // 196
    int nA = (E + CHUNK - 1) / CHUNK;     // 391

    char* ws = (char*)d_ws;
    size_t off = 0;
    auto alloc = [&](size_t bytes) -> char* {
        char* ptr = ws + off;
        off += (bytes + 255) & ~(size_t)255;
        return ptr;
    };
    int* gcur          = (int*)alloc((size_t)nb * 4);
    int* binned        = (int*)alloc((size_t)nb * CAPB * 4);
    int4* rowext       = (int4*)alloc((size_t)N * 16);
    float* dis         = (float*)alloc((size_t)N * 4);
    int* csr           = (int*)alloc((size_t)nb * PCAP * 4);
    _Float16* Wt1      = (_Float16*)alloc(128 * 128 * 2);
    _Float16* Wt2      = (_Float16*)alloc(128 * 128 * 2);
    unsigned char* buf8 = (unsigned char*)alloc((size_t)(N + 1) * D_FEAT);  // +1 zero row
    _Float16* bufH     = (_Float16*)alloc((size_t)N * D_FEAT * 2);

    hipMemsetAsync(gcur, 0, (size_t)nb * 4, stream);

    binA_kernel<<<nA, 256, 0, stream>>>(edges, gcur, binned, E, nb);
    binB_kernel<<<nb, 256, 0, stream>>>(binned, gcur, dis, rowext, csr, N, nb);
    wprep_kernel<<<64, 256, 0, stream>>>(W1, W2, Wt1, Wt2,
                                         (unsigned int*)(buf8 + (size_t)N * D_FEAT));

    int gAgg = (N + 1) / 2;     // 128-thr blocks, 2 waves each, 1 wave per node
    int gGemm = (N + 63) / 64;
    gemm_mfma_kernel<false><<<gGemm, 256, 0, stream>>>((const void*)x, Wt1, dis, buf8, N);
    agg_kernel<<<gAgg, 128, 0, stream>>>(buf8, rowext, csr, b1, bufH, N);
    gemm_mfma_kernel<true><<<gGemm, 256, 0, stream>>>((const void*)bufH, Wt2, dis, buf8, N);
    agg_kernel<<<gAgg, 128, 0, stream>>>(buf8, rowext, csr, b2, bufH, N);
    poolhead_kernel<<<G, 512, 0, stream>>>(bufH, batch, fc1w, fc1b, fc2w, fc2b, out, N);
}

// Round 6
// 257.665 us; speedup vs baseline: 1.5985x; 1.0401x over previous
//
#include <hip/hip_runtime.h>
#include <hip/hip_fp16.h>
#include <math.h>

// GCN: h1 = relu(Agg(x@W1)+b1); h2 = relu(Agg(h1@W2)+b2); pooled = segment_mean(h2);
// out = log_softmax(relu(pooled@fc1+b)@fc2+b)
// buf8[s] = fp8(dis[s] * (x@W)[s]); Agg(v) = relu(dis[v]*(row_v + sum row_s) + b).
// CSR: fixed per-bucket stride (PCAP); padded to multiple of 16, dummy src=N -> zero row.
// R2: agg1+gemm2 fusion REGRESSED (63.4us) — barrier serialized gather MLP. Reverted.
// R3: global-atomic CSR build REGRESSED (scat 127us). Reverted to LDS binning.
// R4/R5: int4-csr + cndmask + 128thr agg = 42.4 vs 40.4 (null/worse). Two different
// structures both ~40-42us @ 89MB L2-miss, ~2.7TB/s -> fabric-floor hypothesis.
// R6: agg reverted to R1 inner form (scalar csr slot loads, 256thr) + packed rowext +
// 32-slot unroll (16 gathers in flight per half-wave) as the latency-vs-fabric probe.
// wprep folded into binB launch (blocks >= nb).

#define D_FEAT 128
#define BSHIFT 9
#define BNODES 512
#define CHUNK 4096
#define CAPB 16384
#define PCAP 16384
#define CAP 10240

using half8   = __attribute__((ext_vector_type(8))) _Float16;
using half4   = __attribute__((ext_vector_type(4))) _Float16;
using floatx4 = __attribute__((ext_vector_type(4))) float;
using floatx2 = __attribute__((ext_vector_type(2))) float;

// ---- single-pass binning: binned[b*CAPB + pos] = (dstlow<<17)|src ----
__global__ void __launch_bounds__(256) binA_kernel(const int* __restrict__ edges,
                                                   int* __restrict__ gcur,
                                                   int* __restrict__ binned, int E, int nb) {
    __shared__ int h[256];
    __shared__ int cur[256];
    __shared__ int base[256];
    int t = threadIdx.x;
    int c0 = blockIdx.x * CHUNK;
    int sv[CHUNK / 256], bv[CHUNK / 256];
    int i0 = c0 + t * (CHUNK / 256);
    if (i0 + (CHUNK / 256) <= E) {
#pragma unroll
        for (int k = 0; k < CHUNK / 256; k += 4) {
            int4 s4 = *(const int4*)&edges[i0 + k];
            int4 d4 = *(const int4*)&edges[E + i0 + k];
            bv[k + 0] = d4.x >> BSHIFT; sv[k + 0] = ((d4.x & (BNODES - 1)) << 17) | s4.x;
            bv[k + 1] = d4.y >> BSHIFT; sv[k + 1] = ((d4.y & (BNODES - 1)) << 17) | s4.y;
            bv[k + 2] = d4.z >> BSHIFT; sv[k + 2] = ((d4.z & (BNODES - 1)) << 17) | s4.z;
            bv[k + 3] = d4.w >> BSHIFT; sv[k + 3] = ((d4.w & (BNODES - 1)) << 17) | s4.w;
        }
    } else {
#pragma unroll
        for (int k = 0; k < CHUNK / 256; ++k) {
            int i = i0 + k;
            if (i < E) {
                int s = edges[i], d = edges[E + i];
                bv[k] = d >> BSHIFT;
                sv[k] = ((d & (BNODES - 1)) << 17) | s;
            } else bv[k] = -1;
        }
    }
    h[t] = 0;
    __syncthreads();
#pragma unroll
    for (int k = 0; k < CHUNK / 256; ++k)
        if (bv[k] >= 0) atomicAdd(&h[bv[k]], 1);
    __syncthreads();
    if (t < nb && h[t] > 0) base[t] = atomicAdd(&gcur[t], h[t]);
    cur[t] = 0;
    __syncthreads();
#pragma unroll
    for (int k = 0; k < CHUNK / 256; ++k)
        if (bv[k] >= 0) {
            int b = bv[k];
            int r = atomicAdd(&cur[b], 1);
            int pos = base[b] + r;
            if (pos < CAPB) binned[b * CAPB + pos] = sv[k];
        }
}

// ---- binB (+wprep tail blocks): per bucket: hist -> dis/rowext, scatter, pad ----
__global__ void __launch_bounds__(256) binB_kernel(const int* __restrict__ binned,
                                                   const int* __restrict__ gcur,
                                                   float* __restrict__ dis,
                                                   int4* __restrict__ rowext,
                                                   int* __restrict__ csr,
                                                   const float* __restrict__ W1,
                                                   const float* __restrict__ W2,
                                                   _Float16* __restrict__ Wt1,
                                                   _Float16* __restrict__ Wt2,
                                                   unsigned int* __restrict__ zrow,
                                                   int N, int nb) {
    int b = blockIdx.x;
    int t = threadIdx.x;
    if (b >= nb) {   // wprep: W transpose fp32->fp16 + zero buf8 row N
        int i = (b - nb) * 256 + t;
        int n = i >> 7, k = i & 127;
        Wt1[i] = (_Float16)W1[k * 128 + n];
        Wt2[i] = (_Float16)W2[k * 128 + n];
        if (i < 32) zrow[i] = 0u;
        return;
    }
    __shared__ int hist[BNODES];
    __shared__ int cur[BNODES];
    __shared__ int pend[BNODES];
    __shared__ int sdata[256];
    __shared__ int vals[CAP];
    int node0 = b << BSHIFT;
    int cnt = gcur[b];
    const int* bin = binned + (size_t)b * CAPB;
    hist[t] = 0; hist[t + 256] = 0;
    __syncthreads();
    for (int i = t; i < cnt; i += 256) {
        int v = bin[i];
        if (i < CAP) vals[i] = v;
        atomicAdd(&hist[v >> 17], 1);
    }
    __syncthreads();
    int a0 = hist[2 * t], a1 = hist[2 * t + 1];
    int p0sz = (a0 + 15) & ~15, p1sz = (a1 + 15) & ~15;   // pad to multiple of 16
    int pair = p0sz + p1sz;
    sdata[t] = pair;
    __syncthreads();
    for (int d = 1; d < 256; d <<= 1) {
        int u = (t >= d) ? sdata[t - d] : 0;
        __syncthreads();
        sdata[t] += u;
        __syncthreads();
    }
    int excl = sdata[t] - pair;
    int q0 = b * PCAP + excl, q1 = q0 + p0sz;
    cur[2 * t] = q0;
    cur[2 * t + 1] = q1;
    pend[2 * t] = q1;
    pend[2 * t + 1] = q1 + p1sz;
    int n0 = node0 + 2 * t, n1 = node0 + 2 * t + 1;
    if (n0 < N) {
        float d0 = rsqrtf((float)a0 + 1.0f);
        dis[n0] = d0;
        rowext[n0] = (int4){q0, q1, __float_as_int(d0), 0};
    }
    if (n1 < N) {
        float d1 = rsqrtf((float)a1 + 1.0f);
        dis[n1] = d1;
        rowext[n1] = (int4){q1, q1 + p1sz, __float_as_int(d1), 0};
    }
    __syncthreads();
    for (int i = t; i < cnt; i += 256) {
        int v = (i < CAP) ? vals[i] : bin[i];
        int p = atomicAdd(&cur[v >> 17], 1);
        csr[p] = v & 0x1FFFF;
    }
    __syncthreads();
    for (int i = t; i < BNODES; i += 256) {
        int e = pend[i];
        for (int p = cur[i]; p < e; ++p) csr[p] = N;   // dummy -> zero row
    }
}

// Y8[row,:] = fp8_e4m3( dis[row] * (X[row,:] @ W) ) via fp16 MFMA.
template <bool HALF_IN>
__global__ void __launch_bounds__(256) gemm_mfma_kernel(const void* __restrict__ Xv,
                                                        const _Float16* __restrict__ WtG,
                                                        const float* __restrict__ dis,
                                                        unsigned char* __restrict__ Y8, int N) {
    __shared__ _Float16 wt[128][136];
    int t = threadIdx.x;
    int row0 = blockIdx.x * 64;

#pragma unroll
    for (int i = 0; i < 8; ++i) {
        int c = t + i * 256;
        int r = c >> 4, c8 = (c & 15) * 8;
        *(half8*)&wt[r][c8] = *(const half8*)&WtG[r * 128 + c8];
    }

    int wave = t >> 6, lane = t & 63;
    int m = lane & 15, quad = lane >> 4;
    int grow = row0 + wave * 16 + m;

    half8 a[4];
    if (grow < N) {
        if (HALF_IN) {
            const _Float16* Xp = (const _Float16*)Xv;
#pragma unroll
            for (int k = 0; k < 4; ++k)
                a[k] = *(const half8*)&Xp[(size_t)grow * 128 + k * 32 + quad * 8];
        } else {
            const float* Xp = (const float*)Xv;
#pragma unroll
            for (int k = 0; k < 4; ++k) {
                float4 v0 = *(const float4*)&Xp[(size_t)grow * 128 + k * 32 + quad * 8];
                float4 v1 = *(const float4*)&Xp[(size_t)grow * 128 + k * 32 + quad * 8 + 4];
                a[k] = (half8){(_Float16)v0.x, (_Float16)v0.y, (_Float16)v0.z, (_Float16)v0.w,
                               (_Float16)v1.x, (_Float16)v1.y, (_Float16)v1.z, (_Float16)v1.w};
            }
        }
    } else {
#pragma unroll
        for (int k = 0; k < 4; ++k) a[k] = (half8){};
    }
    __syncthreads();

    floatx4 acc[8];
#pragma unroll
    for (int nt = 0; nt < 8; ++nt) acc[nt] = (floatx4){0.f, 0.f, 0.f, 0.f};
#pragma unroll
    for (int nt = 0; nt < 8; ++nt) {
#pragma unroll
        for (int k = 0; k < 4; ++k) {
            half8 bfr = *(const half8*)&wt[nt * 16 + m][k * 32 + quad * 8];
            acc[nt] = __builtin_amdgcn_mfma_f32_16x16x32_f16(a[k], bfr, acc[nt], 0, 0, 0);
        }
    }
    int orow = row0 + wave * 16 + quad * 4;
#pragma unroll
    for (int r = 0; r < 4; ++r) {
        int row = orow + r;
        if (row < N) {
            float dr = dis[row];
#pragma unroll
            for (int nt = 0; nt < 8; ++nt) {
                float v = acc[nt][r] * dr;
                unsigned char q =
                    (unsigned char)(__builtin_amdgcn_cvt_pk_fp8_f32(v, v, 0, false) & 0xff);
                Y8[(size_t)row * 128 + nt * 16 + m] = q;
            }
        }
    }
}

// One wave per dst node over pre-scaled fp8 rows; half-wave per edge, plain adds.
// R6: R1 inner form (scalar slot loads, 256thr) + packed rowext + 32-slot unroll
// (16 gathers in flight per half-wave) with 16-slot tail. len always multiple of 16.
__global__ void __launch_bounds__(256) agg_kernel(const unsigned char* __restrict__ H8,
                                                  const int4* __restrict__ rowext,
                                                  const int* __restrict__ csr,
                                                  const float* __restrict__ bias,
                                                  _Float16* __restrict__ out, int N) {
    int v = (blockIdx.x * blockDim.x + threadIdx.x) >> 6;
    int lane = threadIdx.x & 63;
    if (v >= N) return;
    int half = lane >> 5, sl = lane & 31;
    int4 re = rowext[v];
    int r0 = re.x, len = re.y - re.x;
    float dv = __int_as_float(re.z);
    unsigned fo = (unsigned)(sl << 2);

    floatx2 a01, a23;
    {   // self row (pre-scaled): each half adds 0.5x, sums to 1x after combine
        unsigned int u = *(const unsigned int*)(H8 + (((unsigned)v << 7) | fo));
        floatx2 lo = __builtin_amdgcn_cvt_pk_f32_fp8(u, false);
        floatx2 hi = __builtin_amdgcn_cvt_pk_f32_fp8(u, true);
        floatx2 hf = {0.5f, 0.5f};
        a01 = hf * lo;
        a23 = hf * hi;
    }
#define ACC(uu)                                                         \
        {                                                               \
            a01 += __builtin_amdgcn_cvt_pk_f32_fp8(uu, false);          \
            a23 += __builtin_amdgcn_cvt_pk_f32_fp8(uu, true);           \
        }
#define GATHER(ss) *(const unsigned int*)(H8 + (((unsigned)(ss) << 7) | fo))
    int base = 0;
    for (; base + 32 <= len; base += 32) {   // 16 slots per half: 16 gathers in flight
        int e = r0 + base + half;
        int s0 = csr[e],      s1 = csr[e + 2],  s2 = csr[e + 4],  s3 = csr[e + 6];
        int s4 = csr[e + 8],  s5 = csr[e + 10], s6 = csr[e + 12], s7 = csr[e + 14];
        int s8 = csr[e + 16], s9 = csr[e + 18], sa = csr[e + 20], sb = csr[e + 22];
        int sc = csr[e + 24], sd = csr[e + 26], se = csr[e + 28], sf = csr[e + 30];
        unsigned int u0 = GATHER(s0), u1 = GATHER(s1), u2 = GATHER(s2), u3 = GATHER(s3);
        unsigned int u4 = GATHER(s4), u5 = GATHER(s5), u6 = GATHER(s6), u7 = GATHER(s7);
        unsigned int u8 = GATHER(s8), u9 = GATHER(s9), ua = GATHER(sa), ub = GATHER(sb);
        unsigned int uc = GATHER(sc), ud = GATHER(sd), ue = GATHER(se), uf = GATHER(sf);
        ACC(u0) ACC(u1) ACC(u2) ACC(u3) ACC(u4) ACC(u5) ACC(u6) ACC(u7)
        ACC(u8) ACC(u9) ACC(ua) ACC(ub) ACC(uc) ACC(ud) ACC(ue) ACC(uf)
    }
    if (base + 16 <= len) {                  // tail: 8 slots per half
        int e = r0 + base + half;
        int s0 = csr[e],      s1 = csr[e + 2],  s2 = csr[e + 4],  s3 = csr[e + 6];
        int s4 = csr[e + 8],  s5 = csr[e + 10], s6 = csr[e + 12], s7 = csr[e + 14];
        unsigned int u0 = GATHER(s0), u1 = GATHER(s1), u2 = GATHER(s2), u3 = GATHER(s3);
        unsigned int u4 = GATHER(s4), u5 = GATHER(s5), u6 = GATHER(s6), u7 = GATHER(s7);
        ACC(u0) ACC(u1) ACC(u2) ACC(u3) ACC(u4) ACC(u5) ACC(u6) ACC(u7)
    }
#undef GATHER
#undef ACC
    a01[0] += __shfl_xor(a01[0], 32, 64);
    a01[1] += __shfl_xor(a01[1], 32, 64);
    a23[0] += __shfl_xor(a23[0], 32, 64);
    a23[1] += __shfl_xor(a23[1], 32, 64);
    if (half == 0) {
        float4 b = *(const float4*)&bias[sl * 4];
        half4 o = {(_Float16)fmaxf(dv * a01[0] + b.x, 0.f),
                   (_Float16)fmaxf(dv * a01[1] + b.y, 0.f),
                   (_Float16)fmaxf(dv * a23[0] + b.z, 0.f),
                   (_Float16)fmaxf(dv * a23[1] + b.w, 0.f)};
        *(half4*)&out[(size_t)v * 128 + sl * 4] = o;
    }
}

__device__ __forceinline__ int lower_bound_i(const int* a, int n, int key) {
    int lo = 0, hi = n;
    while (lo < hi) {
        int mid = (lo + hi) >> 1;
        if (a[mid] < key) lo = mid + 1;
        else hi = mid;
    }
    return lo;
}

// Fused pool + head: one block (512 thr) per graph.
__global__ void __launch_bounds__(512) poolhead_kernel(const _Float16* __restrict__ H,
                                                       const int* __restrict__ batch,
                                                       const float* __restrict__ fc1w,
                                                       const float* __restrict__ fc1b,
                                                       const float* __restrict__ fc2w,
                                                       const float* __restrict__ fc2b,
                                                       float* __restrict__ out, int N) {
    __shared__ int range[2];
    __shared__ float part[4][128];
    __shared__ float p[128];
    __shared__ float r0s[128], r1s[128];
    int g = blockIdx.x;
    int t = threadIdx.x;
    int j = t & 127, rg = t >> 7;
    if (t < 2) range[t] = lower_bound_i(batch, N, g + t);
    __syncthreads();
    int lo = range[0], hi = range[1];
    float s = 0.f;
    for (int v = lo + rg; v < hi; v += 4) s += (float)H[(size_t)v * 128 + j];
    part[rg][j] = s;
    __syncthreads();
    if (rg == 0) {
        float tot = part[0][j] + part[1][j] + part[2][j] + part[3][j];
        p[j] = tot / fmaxf((float)(hi - lo), 1.0f);
    }
    __syncthreads();
    if (t < 128) {
        float acc = fc1b[t];
#pragma unroll 8
        for (int k = 0; k < 128; ++k) acc = fmaf(p[k], fc1w[k * 128 + t], acc);
        float gv = fmaxf(acc, 0.f);
        r0s[t] = gv * fc2w[t * 2 + 0];
        r1s[t] = gv * fc2w[t * 2 + 1];
    }
    __syncthreads();
    for (int st = 64; st > 0; st >>= 1) {
        if (t < st) {
            r0s[t] += r0s[t + st];
            r1s[t] += r1s[t + st];
        }
        __syncthreads();
    }
    if (t == 0) {
        float l0 = r0s[0] + fc2b[0];
        float l1 = r1s[0] + fc2b[1];
        float m = fmaxf(l0, l1);
        float lse = m + logf(expf(l0 - m) + expf(l1 - m));
        out[g * 2 + 0] = l0 - lse;
        out[g * 2 + 1] = l1 - lse;
    }
}

extern "C" void kernel_launch(void* const* d_in, const int* in_sizes, int n_in,
                              void* d_out, int out_size, void* d_ws, size_t ws_size,
                              hipStream_t stream) {
    const float* x    = (const float*)d_in[0];
    const int* edges  = (const int*)d_in[1];
    const int* batch  = (const int*)d_in[2];
    const float* W1   = (const float*)d_in[3];
    const float* b1   = (const float*)d_in[4];
    const float* W2   = (const float*)d_in[5];
    const float* b2   = (const float*)d_in[6];
    const float* fc1w = (const float*)d_in[7];
    const float* fc1b = (const float*)d_in[8];
    const float* fc2w = (const float*)d_in[9];
    const float* fc2b = (const float*)d_in[10];
    float* out = (float*)d_out;

    int N = in_sizes[2];        // 100000
    int E = in_sizes[1] / 2;    // 1600000
    int G = out_size / 2;       // 1024
    int nb = (N + BNODES - 1) / BNODES;   // 196
    int nA = (E + CHUNK - 1) / CHUNK;     // 391

    char* ws = (char*)d_ws;
    size_t off = 0;
    auto alloc = [&](size_t bytes) -> char* {
        char* ptr = ws + off;
        off += (bytes + 255) & ~(size_t)255;
        return ptr;
    };
    int* gcur          = (int*)alloc((size_t)nb * 4);
    int* binned        = (int*)alloc((size_t)nb * CAPB * 4);
    int4* rowext       = (int4*)alloc((size_t)N * 16);
    float* dis         = (float*)alloc((size_t)N * 4);
    int* csr           = (int*)alloc((size_t)nb * PCAP * 4);
    _Float16* Wt1      = (_Float16*)alloc(128 * 128 * 2);
    _Float16* Wt2      = (_Float16*)alloc(128 * 128 * 2);
    unsigned char* buf8 = (unsigned char*)alloc((size_t)(N + 1) * D_FEAT);  // +1 zero row
    _Float16* bufH     = (_Float16*)alloc((size_t)N * D_FEAT * 2);

    hipMemsetAsync(gcur, 0, (size_t)nb * 4, stream);

    binA_kernel<<<nA, 256, 0, stream>>>(edges, gcur, binned, E, nb);
    binB_kernel<<<nb + 64, 256, 0, stream>>>(binned, gcur, dis, rowext, csr,
                                             W1, W2, Wt1, Wt2,
                                             (unsigned int*)(buf8 + (size_t)N * D_FEAT),
                                             N, nb);

    int gAgg = (N * 64 + 255) / 256;
    int gGemm = (N + 63) / 64;
    gemm_mfma_kernel<false><<<gGemm, 256, 0, stream>>>((const void*)x, Wt1, dis, buf8, N);
    agg_kernel<<<gAgg, 256, 0, stream>>>(buf8, rowext, csr, b1, bufH, N);
    gemm_mfma_kernel<true><<<gGemm, 256, 0, stream>>>((const void*)bufH, Wt2, dis, buf8, N);
    agg_kernel<<<gAgg, 256, 0, stream>>>(buf8, rowext, csr, b2, bufH, N);
    poolhead_kernel<<<G, 512, 0, stream>>>(bufH, batch, fc1w, fc1b, fc2w, fc2b, out, N);
}

// Round 7
// 252.092 us; speedup vs baseline: 1.6339x; 1.0221x over previous
//
#include <hip/hip_runtime.h>
#include <hip/hip_fp16.h>
#include <math.h>

// GCN: h1 = relu(Agg(x@W1)+b1); h2 = relu(Agg(h1@W2)+b2); pooled = segment_mean(h2);
// out = log_softmax(relu(pooled@fc1+b)@fc2+b)
// buf8[s] = fp8(dis[s] * (x@W)[s]); Agg(v) = relu(dis[v]*(row_v + sum row_s) + b).
// CSR: fixed per-bucket stride (PCAP); padded to multiple of 16, dummy src=N -> zero row.
// R2: agg1+gemm2 fusion REGRESSED (63.4us, barrier serialized gather MLP). Reverted.
// R3: global-atomic CSR build REGRESSED (scat 127us fetch-add). Reverted to LDS binning.
// R4/R5: int4-csr agg null (42.4 vs 40.4). R6: 32-slot unroll (16 gathers in flight
// per half) + packed rowext + wprep fold: 266.7 -> 257.7us; agg ~37us each, ~2.4TB/s
// random-line plateau. Fixed in-window harness poison fills ~125us (3x256MiB).
// R7: binning split BSHIFT 9->8 (391 buckets of 256 nodes): binB serial work halves,
// all edges LDS-resident (CAPB==CAP=8192); binA bucket arrays widened to 512.

#define D_FEAT 128
#define BSHIFT 8
#define BNODES 256
#define CHUNK 4096
#define CAPB 8192
#define PCAP 12288

using half8   = __attribute__((ext_vector_type(8))) _Float16;
using half4   = __attribute__((ext_vector_type(4))) _Float16;
using floatx4 = __attribute__((ext_vector_type(4))) float;
using floatx2 = __attribute__((ext_vector_type(2))) float;

// ---- single-pass binning: binned[b*CAPB + pos] = (dstlow<<17)|src ----
__global__ void __launch_bounds__(256) binA_kernel(const int* __restrict__ edges,
                                                   int* __restrict__ gcur,
                                                   int* __restrict__ binned, int E, int nb) {
    __shared__ int h[512];
    __shared__ int cur[512];
    __shared__ int base[512];
    int t = threadIdx.x;
    int c0 = blockIdx.x * CHUNK;
    int sv[CHUNK / 256], bv[CHUNK / 256];
    int i0 = c0 + t * (CHUNK / 256);
    if (i0 + (CHUNK / 256) <= E) {
#pragma unroll
        for (int k = 0; k < CHUNK / 256; k += 4) {
            int4 s4 = *(const int4*)&edges[i0 + k];
            int4 d4 = *(const int4*)&edges[E + i0 + k];
            bv[k + 0] = d4.x >> BSHIFT; sv[k + 0] = ((d4.x & (BNODES - 1)) << 17) | s4.x;
            bv[k + 1] = d4.y >> BSHIFT; sv[k + 1] = ((d4.y & (BNODES - 1)) << 17) | s4.y;
            bv[k + 2] = d4.z >> BSHIFT; sv[k + 2] = ((d4.z & (BNODES - 1)) << 17) | s4.z;
            bv[k + 3] = d4.w >> BSHIFT; sv[k + 3] = ((d4.w & (BNODES - 1)) << 17) | s4.w;
        }
    } else {
#pragma unroll
        for (int k = 0; k < CHUNK / 256; ++k) {
            int i = i0 + k;
            if (i < E) {
                int s = edges[i], d = edges[E + i];
                bv[k] = d >> BSHIFT;
                sv[k] = ((d & (BNODES - 1)) << 17) | s;
            } else bv[k] = -1;
        }
    }
    h[t] = 0; h[t + 256] = 0;
    __syncthreads();
#pragma unroll
    for (int k = 0; k < CHUNK / 256; ++k)
        if (bv[k] >= 0) atomicAdd(&h[bv[k]], 1);
    __syncthreads();
    for (int j = t; j < 512; j += 256) {
        if (j < nb && h[j] > 0) base[j] = atomicAdd(&gcur[j], h[j]);
        cur[j] = 0;
    }
    __syncthreads();
#pragma unroll
    for (int k = 0; k < CHUNK / 256; ++k)
        if (bv[k] >= 0) {
            int b = bv[k];
            int r = atomicAdd(&cur[b], 1);
            int pos = base[b] + r;
            if (pos < CAPB) binned[b * CAPB + pos] = sv[k];
        }
}

// ---- binB (+wprep tail blocks): per 256-node bucket: hist -> dis/rowext/dummies,
// scatter from LDS (all edges fit: CAPB==CAP) ----
__global__ void __launch_bounds__(256) binB_kernel(const int* __restrict__ binned,
                                                   const int* __restrict__ gcur,
                                                   float* __restrict__ dis,
                                                   int4* __restrict__ rowext,
                                                   int* __restrict__ csr,
                                                   const float* __restrict__ W1,
                                                   const float* __restrict__ W2,
                                                   _Float16* __restrict__ Wt1,
                                                   _Float16* __restrict__ Wt2,
                                                   unsigned int* __restrict__ zrow,
                                                   int N, int nb) {
    int b = blockIdx.x;
    int t = threadIdx.x;
    if (b >= nb) {   // wprep: W transpose fp32->fp16 + zero buf8 row N
        int i = (b - nb) * 256 + t;
        int n = i >> 7, k = i & 127;
        Wt1[i] = (_Float16)W1[k * 128 + n];
        Wt2[i] = (_Float16)W2[k * 128 + n];
        if (i < 32) zrow[i] = 0u;
        return;
    }
    __shared__ int hist[BNODES];
    __shared__ int cur[BNODES];
    __shared__ int sdata[256];
    __shared__ int vals[CAPB];
    int node0 = b << BSHIFT;
    int cnt = gcur[b];
    if (cnt > CAPB) cnt = CAPB;
    const int* bin = binned + (size_t)b * CAPB;
    hist[t] = 0;
    __syncthreads();
    for (int i = t; i < cnt; i += 256) {
        int v = bin[i];
        vals[i] = v;
        atomicAdd(&hist[v >> 17], 1);
    }
    __syncthreads();
    int a = hist[t];
    int psz = (a + 15) & ~15;   // pad to multiple of 16
    sdata[t] = psz;
    __syncthreads();
    for (int d = 1; d < 256; d <<= 1) {
        int u = (t >= d) ? sdata[t - d] : 0;
        __syncthreads();
        sdata[t] += u;
        __syncthreads();
    }
    int q0 = b * PCAP + sdata[t] - psz;
    cur[t] = q0;
    int n = node0 + t;
    if (n < N) {
        float d0 = rsqrtf((float)a + 1.0f);
        dis[n] = d0;
        rowext[n] = (int4){q0, q0 + psz, __float_as_int(d0), 0};
        for (int p = q0 + a; p < q0 + psz; ++p) csr[p] = N;   // dummy -> zero row
    }
    __syncthreads();
    for (int i = t; i < cnt; i += 256) {
        int v = vals[i];
        int p = atomicAdd(&cur[v >> 17], 1);
        csr[p] = v & 0x1FFFF;
    }
}

// Y8[row,:] = fp8_e4m3( dis[row] * (X[row,:] @ W) ) via fp16 MFMA.
template <bool HALF_IN>
__global__ void __launch_bounds__(256) gemm_mfma_kernel(const void* __restrict__ Xv,
                                                        const _Float16* __restrict__ WtG,
                                                        const float* __restrict__ dis,
                                                        unsigned char* __restrict__ Y8, int N) {
    __shared__ _Float16 wt[128][136];
    int t = threadIdx.x;
    int row0 = blockIdx.x * 64;

#pragma unroll
    for (int i = 0; i < 8; ++i) {
        int c = t + i * 256;
        int r = c >> 4, c8 = (c & 15) * 8;
        *(half8*)&wt[r][c8] = *(const half8*)&WtG[r * 128 + c8];
    }

    int wave = t >> 6, lane = t & 63;
    int m = lane & 15, quad = lane >> 4;
    int grow = row0 + wave * 16 + m;

    half8 a[4];
    if (grow < N) {
        if (HALF_IN) {
            const _Float16* Xp = (const _Float16*)Xv;
#pragma unroll
            for (int k = 0; k < 4; ++k)
                a[k] = *(const half8*)&Xp[(size_t)grow * 128 + k * 32 + quad * 8];
        } else {
            const float* Xp = (const float*)Xv;
#pragma unroll
            for (int k = 0; k < 4; ++k) {
                float4 v0 = *(const float4*)&Xp[(size_t)grow * 128 + k * 32 + quad * 8];
                float4 v1 = *(const float4*)&Xp[(size_t)grow * 128 + k * 32 + quad * 8 + 4];
                a[k] = (half8){(_Float16)v0.x, (_Float16)v0.y, (_Float16)v0.z, (_Float16)v0.w,
                               (_Float16)v1.x, (_Float16)v1.y, (_Float16)v1.z, (_Float16)v1.w};
            }
        }
    } else {
#pragma unroll
        for (int k = 0; k < 4; ++k) a[k] = (half8){};
    }
    __syncthreads();

    floatx4 acc[8];
#pragma unroll
    for (int nt = 0; nt < 8; ++nt) acc[nt] = (floatx4){0.f, 0.f, 0.f, 0.f};
#pragma unroll
    for (int nt = 0; nt < 8; ++nt) {
#pragma unroll
        for (int k = 0; k < 4; ++k) {
            half8 bfr = *(const half8*)&wt[nt * 16 + m][k * 32 + quad * 8];
            acc[nt] = __builtin_amdgcn_mfma_f32_16x16x32_f16(a[k], bfr, acc[nt], 0, 0, 0);
        }
    }
    int orow = row0 + wave * 16 + quad * 4;
#pragma unroll
    for (int r = 0; r < 4; ++r) {
        int row = orow + r;
        if (row < N) {
            float dr = dis[row];
#pragma unroll
            for (int nt = 0; nt < 8; ++nt) {
                float v = acc[nt][r] * dr;
                unsigned char q =
                    (unsigned char)(__builtin_amdgcn_cvt_pk_fp8_f32(v, v, 0, false) & 0xff);
                Y8[(size_t)row * 128 + nt * 16 + m] = q;
            }
        }
    }
}

// One wave per dst node over pre-scaled fp8 rows; half-wave per edge, plain adds.
// R6: packed rowext + 32-slot unroll (16 gathers in flight per half-wave), 16-slot tail.
__global__ void __launch_bounds__(256) agg_kernel(const unsigned char* __restrict__ H8,
                                                  const int4* __restrict__ rowext,
                                                  const int* __restrict__ csr,
                                                  const float* __restrict__ bias,
                                                  _Float16* __restrict__ out, int N) {
    int v = (blockIdx.x * blockDim.x + threadIdx.x) >> 6;
    int lane = threadIdx.x & 63;
    if (v >= N) return;
    int half = lane >> 5, sl = lane & 31;
    int4 re = rowext[v];
    int r0 = re.x, len = re.y - re.x;
    float dv = __int_as_float(re.z);
    unsigned fo = (unsigned)(sl << 2);

    floatx2 a01, a23;
    {   // self row (pre-scaled): each half adds 0.5x, sums to 1x after combine
        unsigned int u = *(const unsigned int*)(H8 + (((unsigned)v << 7) | fo));
        floatx2 lo = __builtin_amdgcn_cvt_pk_f32_fp8(u, false);
        floatx2 hi = __builtin_amdgcn_cvt_pk_f32_fp8(u, true);
        floatx2 hf = {0.5f, 0.5f};
        a01 = hf * lo;
        a23 = hf * hi;
    }
#define ACC(uu)                                                         \
        {                                                               \
            a01 += __builtin_amdgcn_cvt_pk_f32_fp8(uu, false);          \
            a23 += __builtin_amdgcn_cvt_pk_f32_fp8(uu, true);           \
        }
#define GATHER(ss) *(const unsigned int*)(H8 + (((unsigned)(ss) << 7) | fo))
    int base = 0;
    for (; base + 32 <= len; base += 32) {   // 16 slots per half: 16 gathers in flight
        int e = r0 + base + half;
        int s0 = csr[e],      s1 = csr[e + 2],  s2 = csr[e + 4],  s3 = csr[e + 6];
        int s4 = csr[e + 8],  s5 = csr[e + 10], s6 = csr[e + 12], s7 = csr[e + 14];
        int s8 = csr[e + 16], s9 = csr[e + 18], sa = csr[e + 20], sb = csr[e + 22];
        int sc = csr[e + 24], sd = csr[e + 26], se = csr[e + 28], sf = csr[e + 30];
        unsigned int u0 = GATHER(s0), u1 = GATHER(s1), u2 = GATHER(s2), u3 = GATHER(s3);
        unsigned int u4 = GATHER(s4), u5 = GATHER(s5), u6 = GATHER(s6), u7 = GATHER(s7);
        unsigned int u8 = GATHER(s8), u9 = GATHER(s9), ua = GATHER(sa), ub = GATHER(sb);
        unsigned int uc = GATHER(sc), ud = GATHER(sd), ue = GATHER(se), uf = GATHER(sf);
        ACC(u0) ACC(u1) ACC(u2) ACC(u3) ACC(u4) ACC(u5) ACC(u6) ACC(u7)
        ACC(u8) ACC(u9) ACC(ua) ACC(ub) ACC(uc) ACC(ud) ACC(ue) ACC(uf)
    }
    if (base + 16 <= len) {                  // tail: 8 slots per half
        int e = r0 + base + half;
        int s0 = csr[e],      s1 = csr[e + 2],  s2 = csr[e + 4],  s3 = csr[e + 6];
        int s4 = csr[e + 8],  s5 = csr[e + 10], s6 = csr[e + 12], s7 = csr[e + 14];
        unsigned int u0 = GATHER(s0), u1 = GATHER(s1), u2 = GATHER(s2), u3 = GATHER(s3);
        unsigned int u4 = GATHER(s4), u5 = GATHER(s5), u6 = GATHER(s6), u7 = GATHER(s7);
        ACC(u0) ACC(u1) ACC(u2) ACC(u3) ACC(u4) ACC(u5) ACC(u6) ACC(u7)
    }
#undef GATHER
#undef ACC
    a01[0] += __shfl_xor(a01[0], 32, 64);
    a01[1] += __shfl_xor(a01[1], 32, 64);
    a23[0] += __shfl_xor(a23[0], 32, 64);
    a23[1] += __shfl_xor(a23[1], 32, 64);
    if (half == 0) {
        float4 b = *(const float4*)&bias[sl * 4];
        half4 o = {(_Float16)fmaxf(dv * a01[0] + b.x, 0.f),
                   (_Float16)fmaxf(dv * a01[1] + b.y, 0.f),
                   (_Float16)fmaxf(dv * a23[0] + b.z, 0.f),
                   (_Float16)fmaxf(dv * a23[1] + b.w, 0.f)};
        *(half4*)&out[(size_t)v * 128 + sl * 4] = o;
    }
}

__device__ __forceinline__ int lower_bound_i(const int* a, int n, int key) {
    int lo = 0, hi = n;
    while (lo < hi) {
        int mid = (lo + hi) >> 1;
        if (a[mid] < key) lo = mid + 1;
        else hi = mid;
    }
    return lo;
}

// Fused pool + head: one block (512 thr) per graph.
__global__ void __launch_bounds__(512) poolhead_kernel(const _Float16* __restrict__ H,
                                                       const int* __restrict__ batch,
                                                       const float* __restrict__ fc1w,
                                                       const float* __restrict__ fc1b,
                                                       const float* __restrict__ fc2w,
                                                       const float* __restrict__ fc2b,
                                                       float* __restrict__ out, int N) {
    __shared__ int range[2];
    __shared__ float part[4][128];
    __shared__ float p[128];
    __shared__ float r0s[128], r1s[128];
    int g = blockIdx.x;
    int t = threadIdx.x;
    int j = t & 127, rg = t >> 7;
    if (t < 2) range[t] = lower_bound_i(batch, N, g + t);
    __syncthreads();
    int lo = range[0], hi = range[1];
    float s = 0.f;
    for (int v = lo + rg; v < hi; v += 4) s += (float)H[(size_t)v * 128 + j];
    part[rg][j] = s;
    __syncthreads();
    if (rg == 0) {
        float tot = part[0][j] + part[1][j] + part[2][j] + part[3][j];
        p[j] = tot / fmaxf((float)(hi - lo), 1.0f);
    }
    __syncthreads();
    if (t < 128) {
        float acc = fc1b[t];
#pragma unroll 8
        for (int k = 0; k < 128; ++k) acc = fmaf(p[k], fc1w[k * 128 + t], acc);
        float gv = fmaxf(acc, 0.f);
        r0s[t] = gv * fc2w[t * 2 + 0];
        r1s[t] = gv * fc2w[t * 2 + 1];
    }
    __syncthreads();
    for (int st = 64; st > 0; st >>= 1) {
        if (t < st) {
            r0s[t] += r0s[t + st];
            r1s[t] += r1s[t + st];
        }
        __syncthreads();
    }
    if (t == 0) {
        float l0 = r0s[0] + fc2b[0];
        float l1 = r1s[0] + fc2b[1];
        float m = fmaxf(l0, l1);
        float lse = m + logf(expf(l0 - m) + expf(l1 - m));
        out[g * 2 + 0] = l0 - lse;
        out[g * 2 + 1] = l1 - lse;
    }
}

extern "C" void kernel_launch(void* const* d_in, const int* in_sizes, int n_in,
                              void* d_out, int out_size, void* d_ws, size_t ws_size,
                              hipStream_t stream) {
    const float* x    = (const float*)d_in[0];
    const int* edges  = (const int*)d_in[1];
    const int* batch  = (const int*)d_in[2];
    const float* W1   = (const float*)d_in[3];
    const float* b1   = (const float*)d_in[4];
    const float* W2   = (const float*)d_in[5];
    const float* b2   = (const float*)d_in[6];
    const float* fc1w = (const float*)d_in[7];
    const float* fc1b = (const float*)d_in[8];
    const float* fc2w = (const float*)d_in[9];
    const float* fc2b = (const float*)d_in[10];
    float* out = (float*)d_out;

    int N = in_sizes[2];        // 100000
    int E = in_sizes[1] / 2;    // 1600000
    int G = out_size / 2;       // 1024
    int nb = (N + BNODES - 1) / BNODES;   // 391
    int nA = (E + CHUNK - 1) / CHUNK;     // 391

    char* ws = (char*)d_ws;
    size_t off = 0;
    auto alloc = [&](size_t bytes) -> char* {
        char* ptr = ws + off;
        off += (bytes + 255) & ~(size_t)255;
        return ptr;
    };
    int* gcur          = (int*)alloc((size_t)nb * 4);
    int* binned        = (int*)alloc((size_t)nb * CAPB * 4);
    int4* rowext       = (int4*)alloc((size_t)N * 16);
    float* dis         = (float*)alloc((size_t)N * 4);
    int* csr           = (int*)alloc((size_t)nb * PCAP * 4);
    _Float16* Wt1      = (_Float16*)alloc(128 * 128 * 2);
    _Float16* Wt2      = (_Float16*)alloc(128 * 128 * 2);
    unsigned char* buf8 = (unsigned char*)alloc((size_t)(N + 1) * D_FEAT);  // +1 zero row
    _Float16* bufH     = (_Float16*)alloc((size_t)N * D_FEAT * 2);

    hipMemsetAsync(gcur, 0, (size_t)nb * 4, stream);

    binA_kernel<<<nA, 256, 0, stream>>>(edges, gcur, binned, E, nb);
    binB_kernel<<<nb + 64, 256, 0, stream>>>(binned, gcur, dis, rowext, csr,
                                             W1, W2, Wt1, Wt2,
                                             (unsigned int*)(buf8 + (size_t)N * D_FEAT),
                                             N, nb);

    int gAgg = (N * 64 + 255) / 256;
    int gGemm = (N + 63) / 64;
    gemm_mfma_kernel<false><<<gGemm, 256, 0, stream>>>((const void*)x, Wt1, dis, buf8, N);
    agg_kernel<<<gAgg, 256, 0, stream>>>(buf8, rowext, csr, b1, bufH, N);
    gemm_mfma_kernel<true><<<gGemm, 256, 0, stream>>>((const void*)bufH, Wt2, dis, buf8, N);
    agg_kernel<<<gAgg, 256, 0, stream>>>(buf8, rowext, csr, b2, bufH, N);
    poolhead_kernel<<<G, 512, 0, stream>>>(bufH, batch, fc1w, fc1b, fc2w, fc2b, out, N);
}